// Round 3
// baseline (59.783 us; speedup 1.0000x reference)
//
#include <hip/hip_runtime.h>
#include <stdint.h>

typedef __attribute__((ext_vector_type(4))) float f32x4;
typedef __attribute__((ext_vector_type(8))) short bf16x8;

static constexpr int N_ = 4, C_ = 256, HW_ = 4096;
static constexpr int CO_ = 256, KTAP = 9, KK = 2304;  // KK = C_*KTAP
static constexpr int NSTEP = 72;                      // KK / 32
static constexpr int A_STEP_BYTES = 16 * 64 * 16;     // one K-step plane of A: 16KB

static constexpr size_t NHWC_BYTES = (size_t)N_ * HW_ * C_ * 2;  // 8 MB
static constexpr size_t ABF_OFF    = NHWC_BYTES;
static constexpr size_t ABF_BYTES  = (size_t)NSTEP * A_STEP_BYTES;  // 1.18 MB

__device__ inline unsigned f2bf(float f) {
  unsigned u = __builtin_bit_cast(unsigned, f);
  unsigned r = u + 0x7FFFu + ((u >> 16) & 1u);
  return r >> 16;
}
__device__ inline float asf(unsigned u) { return __builtin_bit_cast(float, u); }

// ---------------- NCHW f32 -> NHWC bf16 ----------------
__global__ __launch_bounds__(256) void k_nchw_to_nhwc(const float* __restrict__ in,
                                                      unsigned short* __restrict__ nhwc) {
  __shared__ float tile[64][65];
  int b = blockIdx.x;
  int n = b >> 8, cg = (b >> 6) & 3, hwg = b & 63;
  int c0 = cg * 64, hw0 = hwg * 64;
  int t = threadIdx.x;
  int col = t & 63, r0 = t >> 6;
  const float* src = in + (size_t)(n * C_ + c0) * HW_ + hw0;
#pragma unroll
  for (int i = 0; i < 16; ++i) {
    int row = r0 + i * 4;
    tile[row][col] = src[(size_t)row * HW_ + col];
  }
  __syncthreads();
  int pr = t >> 2, cc0 = (t & 3) * 16;
  unsigned us[8];
#pragma unroll
  for (int i = 0; i < 8; ++i) {
    unsigned lo = f2bf(tile[cc0 + 2 * i][pr]);
    unsigned hi = f2bf(tile[cc0 + 2 * i + 1][pr]);
    us[i] = lo | (hi << 16);
  }
  unsigned* dst = (unsigned*)(nhwc + (size_t)(n * HW_ + hw0 + pr) * C_ + c0 + cc0);
  ((uint4*)dst)[0] = make_uint4(us[0], us[1], us[2], us[3]);
  ((uint4*)dst)[1] = make_uint4(us[4], us[5], us[6], us[7]);
}

// ---------------- filter f32 [O][C][3][3] -> bf16 fragment-major ----------------
// abf2[((s*16 + rb)*64 + lane)*8 + j]  where s = tap*8 + (c>>5), rb = o>>4,
// lane = ((c>>3)&3)*16 + (o&15), j = c&7.
__global__ __launch_bounds__(256) void k_prep_filter(const float* __restrict__ filt,
                                                     unsigned short* __restrict__ abf2) {
  int gid = blockIdx.x * 256 + threadIdx.x;
  int o = gid >> 8, c = gid & 255;
  const float* f = filt + (size_t)(o * C_ + c) * KTAP;
  int rb = o >> 4;
  int lane = ((c >> 3) & 3) * 16 + (o & 15);
  int j = c & 7;
#pragma unroll
  for (int tap = 0; tap < KTAP; ++tap) {
    int s = tap * 8 + (c >> 5);
    abf2[((size_t)(s * 16 + rb) * 64 + lane) * 8 + j] = (unsigned short)f2bf(f[tap]);
  }
}

struct GBank { uint2 g[8]; f32x4 w; };
struct AFrags { bf16x8 f[4]; };

// bilinear combine of 4 channels from 4 corners -> 4 bf16 (8B) into LDS
__device__ __forceinline__ void buildB4(const uint2* g, f32x4 w, char* dst) {
  float r0 = w.x * asf(g[0].x << 16) + w.y * asf(g[1].x << 16) +
             w.z * asf(g[2].x << 16) + w.w * asf(g[3].x << 16);
  float r1 = w.x * asf(g[0].x & 0xffff0000u) + w.y * asf(g[1].x & 0xffff0000u) +
             w.z * asf(g[2].x & 0xffff0000u) + w.w * asf(g[3].x & 0xffff0000u);
  float r2 = w.x * asf(g[0].y << 16) + w.y * asf(g[1].y << 16) +
             w.z * asf(g[2].y << 16) + w.w * asf(g[3].y << 16);
  float r3 = w.x * asf(g[0].y & 0xffff0000u) + w.y * asf(g[1].y & 0xffff0000u) +
             w.z * asf(g[2].y & 0xffff0000u) + w.w * asf(g[3].y & 0xffff0000u);
  *(uint2*)dst = make_uint2(f2bf(r0) | (f2bf(r1) << 16), f2bf(r2) | (f2bf(r3) << 16));
}

#define MFMA_BF16 __builtin_amdgcn_mfma_f32_16x16x32_bf16

// One phase = 2 K-steps (S, S+1). Consumes B(S),B(S+1) from Bl[RDP]; builds
// B(S+2),B(S+3) into Bl[WRP] from bank GC; issues gathers g(S+4),g(S+5) into GI;
// prefetches A(S+2),A(S+3) into AN. One barrier per phase.
#define PHASE(S, GC, GI, AC, AN, RDP, WRP)                                        \
  do {                                                                            \
    int sa_ = (S) + 2 < NSTEP ? (S) + 2 : NSTEP - 1;                              \
    int sb_ = (S) + 3 < NSTEP ? (S) + 3 : NSTEP - 1;                              \
    int s4_ = (S) + 4 < NSTEP ? (S) + 4 : NSTEP - 1;                              \
    int s5_ = (S) + 5 < NSTEP ? (S) + 5 : NSTEP - 1;                              \
    AN.f[0] = *(const bf16x8*)(aoff0 + (size_t)sa_ * A_STEP_BYTES);               \
    AN.f[1] = *(const bf16x8*)(aoff1 + (size_t)sa_ * A_STEP_BYTES);               \
    AN.f[2] = *(const bf16x8*)(aoff0 + (size_t)sb_ * A_STEP_BYTES);               \
    AN.f[3] = *(const bf16x8*)(aoff1 + (size_t)sb_ * A_STEP_BYTES);               \
    {                                                                             \
      int tp_ = s4_ >> 3;                                                         \
      uint4 ra_ = *(const uint4*)&recA[(tp_ * 64 + p_b) * 4];                     \
      GI.w = *(const f32x4*)&recW[(tp_ * 64 + p_b) * 4];                          \
      unsigned c4_ = (unsigned)((s4_ & 7) * 64);                                  \
      unsigned c5_ = (unsigned)((s5_ & 7) * 64);                                  \
      GI.g[0] = *(const uint2*)(nb_t + ra_.x + c4_);                              \
      GI.g[1] = *(const uint2*)(nb_t + ra_.y + c4_);                              \
      GI.g[2] = *(const uint2*)(nb_t + ra_.z + c4_);                              \
      GI.g[3] = *(const uint2*)(nb_t + ra_.w + c4_);                              \
      GI.g[4] = *(const uint2*)(nb_t + ra_.x + c5_);                              \
      GI.g[5] = *(const uint2*)(nb_t + ra_.y + c5_);                              \
      GI.g[6] = *(const uint2*)(nb_t + ra_.z + c5_);                              \
      GI.g[7] = *(const uint2*)(nb_t + ra_.w + c5_);                              \
    }                                                                             \
    __builtin_amdgcn_sched_barrier(0);                                            \
    {                                                                             \
      const char* bb_ = (const char*)&Bl[0][0] + (RDP) * 8192 + boff;             \
      bf16x8 b0_ = *(const bf16x8*)(bb_ + 0);                                     \
      bf16x8 b1_ = *(const bf16x8*)(bb_ + 256);                                   \
      bf16x8 b2_ = *(const bf16x8*)(bb_ + 512);                                   \
      bf16x8 b3_ = *(const bf16x8*)(bb_ + 768);                                   \
      __builtin_amdgcn_s_setprio(1);                                              \
      acc[0][0] = MFMA_BF16(AC.f[0], b0_, acc[0][0], 0, 0, 0);                    \
      acc[1][0] = MFMA_BF16(AC.f[1], b0_, acc[1][0], 0, 0, 0);                    \
      acc[0][1] = MFMA_BF16(AC.f[0], b1_, acc[0][1], 0, 0, 0);                    \
      acc[1][1] = MFMA_BF16(AC.f[1], b1_, acc[1][1], 0, 0, 0);                    \
      acc[0][2] = MFMA_BF16(AC.f[0], b2_, acc[0][2], 0, 0, 0);                    \
      acc[1][2] = MFMA_BF16(AC.f[1], b2_, acc[1][2], 0, 0, 0);                    \
      acc[0][3] = MFMA_BF16(AC.f[0], b3_, acc[0][3], 0, 0, 0);                    \
      acc[1][3] = MFMA_BF16(AC.f[1], b3_, acc[1][3], 0, 0, 0);                    \
      __builtin_amdgcn_s_setprio(0);                                              \
      bf16x8 b4_ = *(const bf16x8*)(bb_ + 4096 + 0);                              \
      bf16x8 b5_ = *(const bf16x8*)(bb_ + 4096 + 256);                            \
      bf16x8 b6_ = *(const bf16x8*)(bb_ + 4096 + 512);                            \
      bf16x8 b7_ = *(const bf16x8*)(bb_ + 4096 + 768);                            \
      __builtin_amdgcn_s_setprio(1);                                              \
      acc[0][0] = MFMA_BF16(AC.f[2], b4_, acc[0][0], 0, 0, 0);                    \
      acc[1][0] = MFMA_BF16(AC.f[3], b4_, acc[1][0], 0, 0, 0);                    \
      acc[0][1] = MFMA_BF16(AC.f[2], b5_, acc[0][1], 0, 0, 0);                    \
      acc[1][1] = MFMA_BF16(AC.f[3], b5_, acc[1][1], 0, 0, 0);                    \
      acc[0][2] = MFMA_BF16(AC.f[2], b6_, acc[0][2], 0, 0, 0);                    \
      acc[1][2] = MFMA_BF16(AC.f[3], b6_, acc[1][2], 0, 0, 0);                    \
      acc[0][3] = MFMA_BF16(AC.f[2], b7_, acc[0][3], 0, 0, 0);                    \
      acc[1][3] = MFMA_BF16(AC.f[3], b7_, acc[1][3], 0, 0, 0);                    \
      __builtin_amdgcn_s_setprio(0);                                              \
    }                                                                             \
    buildB4(&GC.g[0], GC.w, bwp + (WRP) * 8192 + 0);                              \
    buildB4(&GC.g[4], GC.w, bwp + (WRP) * 8192 + 4096);                           \
    asm volatile("s_waitcnt lgkmcnt(0)" ::: "memory");                            \
    __builtin_amdgcn_s_barrier();                                                 \
    asm volatile("" ::: "memory");                                                \
  } while (0)

// ---------------- fused sample + GEMM ----------------
// 256 blocks (one per output row) x 512 threads (8 waves, wave tile 32 Cout x 64 px)
// B LDS layout per buffer: [half][cq=ch>>3][px][8ch] in 16B chunks (bank-uniform).
__global__ __launch_bounds__(512, 2) void k_dcn_gemm(const unsigned short* __restrict__ nhwc,
                                                     const unsigned short* __restrict__ abf2,
                                                     const float* __restrict__ offs,
                                                     const float* __restrict__ msk,
                                                     float* __restrict__ out) {
  __shared__ __align__(16) unsigned short Bl[2][4096];  // 2 buffers x (2 steps x 4KB)
  __shared__ float recW[KTAP * 64 * 4];
  __shared__ unsigned recA[KTAP * 64 * 4];

  int bid = blockIdx.x;
  int b = ((bid & 7) << 5) | (bid >> 3);  // XCD-aware swizzle (bijective, 256%8==0)
  int n = b >> 6;
  int ho = b & 63;
  int hw0 = ho << 6;
  int t = threadIdx.x;

  // --- per (pixel, tap) sampling records ---
  for (int r = t; r < 576; r += 512) {
    int pl = r / 9;
    int tap = r - pl * 9;
    int hw = hw0 + pl;
    float dy = offs[(size_t)(n * 18 + 2 * tap) * HW_ + hw];
    float dx = offs[(size_t)(n * 18 + 2 * tap + 1) * HW_ + hw];
    float mk = msk[(size_t)(n * 9 + tap) * HW_ + hw];
    float y = (float)(ho - 1 + tap / 3) + dy;
    float x = (float)(pl - 1 + tap % 3) + dx;
    float fy = floorf(y), fx = floorf(x);
    float ly = y - fy, lx = x - fx;
    int y0 = (int)fy, x0 = (int)fx;
    int y1 = y0 + 1, x1 = x0 + 1;
    float vy0 = (y0 >= 0 && y0 < 64) ? 1.f : 0.f;
    float vy1 = (y1 >= 0 && y1 < 64) ? 1.f : 0.f;
    float vx0 = (x0 >= 0 && x0 < 64) ? 1.f : 0.f;
    float vx1 = (x1 >= 0 && x1 < 64) ? 1.f : 0.f;
    int y0c = min(max(y0, 0), 63), y1c = min(max(y1, 0), 63);
    int x0c = min(max(x0, 0), 63), x1c = min(max(x1, 0), 63);
    int base = (tap * 64 + pl) * 4;
    recW[base + 0] = (1.f - ly) * (1.f - lx) * mk * vy0 * vx0;
    recW[base + 1] = (1.f - ly) * lx * mk * vy0 * vx1;
    recW[base + 2] = ly * (1.f - lx) * mk * vy1 * vx0;
    recW[base + 3] = ly * lx * mk * vy1 * vx1;
    recA[base + 0] = (unsigned)((y0c * 64 + x0c) * 512);
    recA[base + 1] = (unsigned)((y0c * 64 + x1c) * 512);
    recA[base + 2] = (unsigned)((y1c * 64 + x0c) * 512);
    recA[base + 3] = (unsigned)((y1c * 64 + x1c) * 512);
  }
  __syncthreads();

  int lane = t & 63, wv = t >> 6;
  int p_b = t >> 3, cg = t & 7;

  const char* aoff0 = (const char*)abf2 + ((wv * 2 + 0) * 64 + lane) * 16;
  const char* aoff1 = (const char*)abf2 + ((wv * 2 + 1) * 64 + lane) * 16;
  const char* nb_t = (const char*)nhwc + (size_t)n * HW_ * C_ * 2 + cg * 8;
  char* bwp = (char*)&Bl[0][0] + ((cg >> 1) * 1024 + p_b * 16 + (cg & 1) * 8);
  const int boff = (lane >> 4) * 1024 + (lane & 15) * 16;

  f32x4 acc[2][4];
#pragma unroll
  for (int mi = 0; mi < 2; ++mi)
#pragma unroll
    for (int ni = 0; ni < 4; ++ni) acc[mi][ni] = (f32x4){0.f, 0.f, 0.f, 0.f};

  GBank gA, gB;
  AFrags aC, aN;

  // --- prologue: gathers for steps 0..3 (all tap 0), A(0,1); build B(0,1) ---
  {
    uint4 ra0 = *(const uint4*)&recA[p_b * 4];
    f32x4 w0 = *(const f32x4*)&recW[p_b * 4];
    gA.w = w0;
    gB.w = w0;
    gA.g[0] = *(const uint2*)(nb_t + ra0.x + 0);
    gA.g[1] = *(const uint2*)(nb_t + ra0.y + 0);
    gA.g[2] = *(const uint2*)(nb_t + ra0.z + 0);
    gA.g[3] = *(const uint2*)(nb_t + ra0.w + 0);
    gA.g[4] = *(const uint2*)(nb_t + ra0.x + 64);
    gA.g[5] = *(const uint2*)(nb_t + ra0.y + 64);
    gA.g[6] = *(const uint2*)(nb_t + ra0.z + 64);
    gA.g[7] = *(const uint2*)(nb_t + ra0.w + 64);
    gB.g[0] = *(const uint2*)(nb_t + ra0.x + 128);
    gB.g[1] = *(const uint2*)(nb_t + ra0.y + 128);
    gB.g[2] = *(const uint2*)(nb_t + ra0.z + 128);
    gB.g[3] = *(const uint2*)(nb_t + ra0.w + 128);
    gB.g[4] = *(const uint2*)(nb_t + ra0.x + 192);
    gB.g[5] = *(const uint2*)(nb_t + ra0.y + 192);
    gB.g[6] = *(const uint2*)(nb_t + ra0.z + 192);
    gB.g[7] = *(const uint2*)(nb_t + ra0.w + 192);
    aC.f[0] = *(const bf16x8*)(aoff0);
    aC.f[1] = *(const bf16x8*)(aoff1);
    aC.f[2] = *(const bf16x8*)(aoff0 + A_STEP_BYTES);
    aC.f[3] = *(const bf16x8*)(aoff1 + A_STEP_BYTES);
    buildB4(&gA.g[0], gA.w, bwp + 0);
    buildB4(&gA.g[4], gA.w, bwp + 4096);
    asm volatile("s_waitcnt lgkmcnt(0)" ::: "memory");
    __builtin_amdgcn_s_barrier();
    asm volatile("" ::: "memory");
  }

  // --- main loop: 36 phases of 2 K-steps each ---
  for (int s = 0; s < NSTEP; s += 4) {
    PHASE(s,     gB, gA, aC, aN, 0, 1);
    PHASE(s + 2, gA, gB, aN, aC, 1, 0);
  }

  // --- epilogue: D row = Cout, col = px ---
  float* ob = out + (size_t)n * CO_ * HW_ + hw0;
#pragma unroll
  for (int mi = 0; mi < 2; ++mi)
#pragma unroll
    for (int ni = 0; ni < 4; ++ni)
#pragma unroll
      for (int j = 0; j < 4; ++j) {
        int o = wv * 32 + mi * 16 + (lane >> 4) * 4 + j;
        int hw = ni * 16 + (lane & 15);
        ob[(size_t)o * HW_ + hw] = acc[mi][ni][j];
      }
}

extern "C" void kernel_launch(void* const* d_in, const int* in_sizes, int n_in,
                              void* d_out, int out_size, void* d_ws, size_t ws_size,
                              hipStream_t stream) {
  const float* inp  = (const float*)d_in[0];
  const float* filt = (const float*)d_in[1];
  const float* offs = (const float*)d_in[2];
  const float* msk  = (const float*)d_in[3];
  float* out = (float*)d_out;
  if (ws_size < ABF_OFF + ABF_BYTES) return;  // ~9.6 MB scratch
  unsigned short* nhwc = (unsigned short*)d_ws;
  unsigned short* abf2 = (unsigned short*)((char*)d_ws + ABF_OFF);

  k_nchw_to_nhwc<<<1024, 256, 0, stream>>>(inp, nhwc);
  k_prep_filter<<<256, 256, 0, stream>>>(filt, abf2);
  k_dcn_gemm<<<256, 512, 0, stream>>>(nhwc, abf2, offs, msk, out);
}

// Round 4
// 56.485 us; speedup vs baseline: 1.0584x; 1.0584x over previous
//
#include <hip/hip_runtime.h>
#include <stdint.h>

typedef __attribute__((ext_vector_type(4))) float f32x4;
typedef __attribute__((ext_vector_type(8))) short bf16x8;

static constexpr int N_ = 4, C_ = 256, HW_ = 4096;
static constexpr int CO_ = 256, KTAP = 9, KK = 2304;  // KK = C_*KTAP
static constexpr int NSTEP = 72;                      // KK / 32
static constexpr int A_STEP_BYTES = 16 * 64 * 16;     // one K-step plane of A: 16KB

static constexpr size_t NHWC_BYTES = (size_t)N_ * HW_ * C_ * 2;  // 8 MB
static constexpr size_t ABF_OFF    = NHWC_BYTES;
static constexpr size_t ABF_BYTES  = (size_t)NSTEP * A_STEP_BYTES;  // 1.18 MB

__device__ inline unsigned f2bf(float f) {
  unsigned u = __builtin_bit_cast(unsigned, f);
  unsigned r = u + 0x7FFFu + ((u >> 16) & 1u);
  return r >> 16;
}
__device__ inline float asf(unsigned u) { return __builtin_bit_cast(float, u); }

// ---------------- NCHW f32 -> NHWC bf16 ----------------
__global__ __launch_bounds__(256) void k_nchw_to_nhwc(const float* __restrict__ in,
                                                      unsigned short* __restrict__ nhwc) {
  __shared__ float tile[64][65];
  int b = blockIdx.x;
  int n = b >> 8, cg = (b >> 6) & 3, hwg = b & 63;
  int c0 = cg * 64, hw0 = hwg * 64;
  int t = threadIdx.x;
  int col = t & 63, r0 = t >> 6;
  const float* src = in + (size_t)(n * C_ + c0) * HW_ + hw0;
#pragma unroll
  for (int i = 0; i < 16; ++i) {
    int row = r0 + i * 4;
    tile[row][col] = src[(size_t)row * HW_ + col];
  }
  __syncthreads();
  int pr = t >> 2, cc0 = (t & 3) * 16;
  unsigned us[8];
#pragma unroll
  for (int i = 0; i < 8; ++i) {
    unsigned lo = f2bf(tile[cc0 + 2 * i][pr]);
    unsigned hi = f2bf(tile[cc0 + 2 * i + 1][pr]);
    us[i] = lo | (hi << 16);
  }
  unsigned* dst = (unsigned*)(nhwc + (size_t)(n * HW_ + hw0 + pr) * C_ + c0 + cc0);
  ((uint4*)dst)[0] = make_uint4(us[0], us[1], us[2], us[3]);
  ((uint4*)dst)[1] = make_uint4(us[4], us[5], us[6], us[7]);
}

// ---------------- filter f32 [O][C][3][3] -> bf16 fragment-major ----------------
// abf2[((s*16 + rb)*64 + lane)*8 + j]  where s = tap*8 + (c>>5), rb = o>>4,
// lane = ((c>>3)&3)*16 + (o&15), j = c&7.
__global__ __launch_bounds__(256) void k_prep_filter(const float* __restrict__ filt,
                                                     unsigned short* __restrict__ abf2) {
  int gid = blockIdx.x * 256 + threadIdx.x;
  int o = gid >> 8, c = gid & 255;
  const float* f = filt + (size_t)(o * C_ + c) * KTAP;
  int rb = o >> 4;
  int lane = ((c >> 3) & 3) * 16 + (o & 15);
  int j = c & 7;
#pragma unroll
  for (int tap = 0; tap < KTAP; ++tap) {
    int s = tap * 8 + (c >> 5);
    abf2[((size_t)(s * 16 + rb) * 64 + lane) * 8 + j] = (unsigned short)f2bf(f[tap]);
  }
}

struct GB { unsigned g[4]; f32x4 w; };

// bilinear combine of 2 channels from 4 corners -> 2 bf16 (4B) into LDS
__device__ __forceinline__ void buildB2(const unsigned* g, f32x4 w, char* dst) {
  float r0 = w.x * asf(g[0] << 16) + w.y * asf(g[1] << 16) +
             w.z * asf(g[2] << 16) + w.w * asf(g[3] << 16);
  float r1 = w.x * asf(g[0] & 0xffff0000u) + w.y * asf(g[1] & 0xffff0000u) +
             w.z * asf(g[2] & 0xffff0000u) + w.w * asf(g[3] & 0xffff0000u);
  *(unsigned*)dst = f2bf(r0) | (f2bf(r1) << 16);
}

#define MFMA_BF16 __builtin_amdgcn_mfma_f32_16x16x32_bf16

// One K-step. Consumes B(S) from buf RDP; builds B(S+1) into buf WRP from bank
// GCON; issues gathers g(S+2) into bank GISS; prefetches A(S+1) into ANXT.
#define PIPE(S, GCON, GISS, ACUR, ANXT, RDP, WRP)                                 \
  do {                                                                            \
    int s1_ = (S) + 1 < NSTEP ? (S) + 1 : NSTEP - 1;                              \
    int s2_ = (S) + 2 < NSTEP ? (S) + 2 : NSTEP - 1;                              \
    ANXT = *(const bf16x8*)(aoff + (size_t)s1_ * A_STEP_BYTES);                   \
    if ((s2_ & 7) == 0) {                                                         \
      int tp_ = s2_ >> 3;                                                         \
      raS = *(const uint4*)&recA[(tp_ * 64 + p_b) * 4];                           \
      wS  = *(const f32x4*)&recW[(tp_ * 64 + p_b) * 4];                           \
    }                                                                             \
    {                                                                             \
      unsigned co_ = (unsigned)((s2_ & 7) * 64);                                  \
      GISS.g[0] = *(const unsigned*)(nb_t + raS.x + co_);                         \
      GISS.g[1] = *(const unsigned*)(nb_t + raS.y + co_);                         \
      GISS.g[2] = *(const unsigned*)(nb_t + raS.z + co_);                         \
      GISS.g[3] = *(const unsigned*)(nb_t + raS.w + co_);                         \
      GISS.w = wS;                                                                \
    }                                                                             \
    __builtin_amdgcn_sched_barrier(0);                                            \
    {                                                                             \
      const char* bb_ = (const char*)&Bl[0][0] + (RDP) * 4096;                    \
      bf16x8 b0_ = *(const bf16x8*)(bb_ + bo0);                                   \
      bf16x8 b1_ = *(const bf16x8*)(bb_ + bo1);                                   \
      bf16x8 b2_ = *(const bf16x8*)(bb_ + bo2);                                   \
      bf16x8 b3_ = *(const bf16x8*)(bb_ + bo3);                                   \
      __builtin_amdgcn_s_setprio(1);                                              \
      acc[0] = MFMA_BF16(ACUR, b0_, acc[0], 0, 0, 0);                             \
      acc[1] = MFMA_BF16(ACUR, b1_, acc[1], 0, 0, 0);                             \
      acc[2] = MFMA_BF16(ACUR, b2_, acc[2], 0, 0, 0);                             \
      acc[3] = MFMA_BF16(ACUR, b3_, acc[3], 0, 0, 0);                             \
      __builtin_amdgcn_s_setprio(0);                                              \
    }                                                                             \
    buildB2(GCON.g, GCON.w, (WRP) ? bw1 : bw0);                                   \
    asm volatile("s_waitcnt lgkmcnt(0)" ::: "memory");                            \
    __builtin_amdgcn_s_barrier();                                                 \
    asm volatile("" ::: "memory");                                                \
  } while (0)

// ---------------- fused sample + GEMM ----------------
// 256 blocks (one per output row) x 1024 threads (16 waves, wave tile 16 Cout x 64 px)
// B LDS layout per step-buffer (4KB): [cq=ch>>3][slot=(px+4cq)&63][8ch as 16B],
// builder thread owns 2 channels: cq = (t&15)>>2, k = t&3 -> 4B at slot*16 + k*4.
__global__ __launch_bounds__(1024, 4) void k_dcn_gemm(const unsigned short* __restrict__ nhwc,
                                                      const unsigned short* __restrict__ abf2,
                                                      const float* __restrict__ offs,
                                                      const float* __restrict__ msk,
                                                      float* __restrict__ out) {
  __shared__ __align__(16) unsigned short Bl[2][2048];  // 2 x 4KB step buffers
  __shared__ float recW[KTAP * 64 * 4];
  __shared__ unsigned recA[KTAP * 64 * 4];

  int bid = blockIdx.x;
  int b = ((bid & 7) << 5) | (bid >> 3);  // XCD-aware swizzle (bijective, 256%8==0)
  int n = b >> 6;
  int ho = b & 63;
  int hw0 = ho << 6;
  int t = threadIdx.x;

  // --- per (pixel, tap) sampling records ---
  for (int r = t; r < 576; r += 1024) {
    int pl = r / 9;
    int tap = r - pl * 9;
    int hw = hw0 + pl;
    float dy = offs[(size_t)(n * 18 + 2 * tap) * HW_ + hw];
    float dx = offs[(size_t)(n * 18 + 2 * tap + 1) * HW_ + hw];
    float mk = msk[(size_t)(n * 9 + tap) * HW_ + hw];
    float y = (float)(ho - 1 + tap / 3) + dy;
    float x = (float)(pl - 1 + tap % 3) + dx;
    float fy = floorf(y), fx = floorf(x);
    float ly = y - fy, lx = x - fx;
    int y0 = (int)fy, x0 = (int)fx;
    int y1 = y0 + 1, x1 = x0 + 1;
    float vy0 = (y0 >= 0 && y0 < 64) ? 1.f : 0.f;
    float vy1 = (y1 >= 0 && y1 < 64) ? 1.f : 0.f;
    float vx0 = (x0 >= 0 && x0 < 64) ? 1.f : 0.f;
    float vx1 = (x1 >= 0 && x1 < 64) ? 1.f : 0.f;
    int y0c = min(max(y0, 0), 63), y1c = min(max(y1, 0), 63);
    int x0c = min(max(x0, 0), 63), x1c = min(max(x1, 0), 63);
    int base = (tap * 64 + pl) * 4;
    recW[base + 0] = (1.f - ly) * (1.f - lx) * mk * vy0 * vx0;
    recW[base + 1] = (1.f - ly) * lx * mk * vy0 * vx1;
    recW[base + 2] = ly * (1.f - lx) * mk * vy1 * vx0;
    recW[base + 3] = ly * lx * mk * vy1 * vx1;
    recA[base + 0] = (unsigned)((y0c * 64 + x0c) * 512);
    recA[base + 1] = (unsigned)((y0c * 64 + x1c) * 512);
    recA[base + 2] = (unsigned)((y1c * 64 + x0c) * 512);
    recA[base + 3] = (unsigned)((y1c * 64 + x1c) * 512);
  }
  __syncthreads();

  int lane = t & 63, wv = t >> 6;
  int p_b = t >> 4;          // builder pixel 0..63
  int cg = t & 15;           // builder channel-pair 0..15 (channels 2cg, 2cg+1)
  int cq = cg >> 2, ck = cg & 3;

  const char* aoff = (const char*)abf2 + ((size_t)(wv * 64 + lane)) * 16;
  const char* nb_t = (const char*)nhwc + (size_t)n * HW_ * C_ * 2 + cg * 4;
  int wbyte = cq * 1024 + (((p_b + 4 * cq) & 63) * 16) + ck * 4;
  char* bw0 = (char*)&Bl[0][0] + wbyte;
  char* bw1 = (char*)&Bl[0][0] + 4096 + wbyte;

  int cqr = lane >> 4;
  int rslot = (lane & 15) + 4 * cqr;
  const int bo0 = cqr * 1024 + ((rslot + 0) & 63) * 16;
  const int bo1 = cqr * 1024 + ((rslot + 16) & 63) * 16;
  const int bo2 = cqr * 1024 + ((rslot + 32) & 63) * 16;
  const int bo3 = cqr * 1024 + ((rslot + 48) & 63) * 16;

  f32x4 acc[4];
#pragma unroll
  for (int ni = 0; ni < 4; ++ni) acc[ni] = (f32x4){0.f, 0.f, 0.f, 0.f};

  GB gA, gB;
  bf16x8 afc, afn;
  uint4 raS;
  f32x4 wS;

  // --- prologue: gathers g(0) -> gA, g(1) -> gB, A(0); build B(0) into buf0 ---
  raS = *(const uint4*)&recA[p_b * 4];  // tap 0
  wS  = *(const f32x4*)&recW[p_b * 4];
  gA.g[0] = *(const unsigned*)(nb_t + raS.x);
  gA.g[1] = *(const unsigned*)(nb_t + raS.y);
  gA.g[2] = *(const unsigned*)(nb_t + raS.z);
  gA.g[3] = *(const unsigned*)(nb_t + raS.w);
  gA.w = wS;
  gB.g[0] = *(const unsigned*)(nb_t + raS.x + 64);
  gB.g[1] = *(const unsigned*)(nb_t + raS.y + 64);
  gB.g[2] = *(const unsigned*)(nb_t + raS.z + 64);
  gB.g[3] = *(const unsigned*)(nb_t + raS.w + 64);
  gB.w = wS;
  afc = *(const bf16x8*)(aoff);
  buildB2(gA.g, gA.w, bw0);
  asm volatile("s_waitcnt lgkmcnt(0)" ::: "memory");
  __builtin_amdgcn_s_barrier();
  asm volatile("" ::: "memory");

  // --- main loop: 72 steps, one barrier per step ---
  for (int s = 0; s < NSTEP; s += 2) {
    PIPE(s,     gB, gA, afc, afn, 0, 1);
    PIPE(s + 1, gA, gB, afn, afc, 1, 0);
  }

  // --- epilogue: D row = Cout (within wave's 16), col = px ---
  float* ob = out + (size_t)n * CO_ * HW_ + hw0;
#pragma unroll
  for (int ni = 0; ni < 4; ++ni)
#pragma unroll
    for (int j = 0; j < 4; ++j) {
      int o = wv * 16 + (lane >> 4) * 4 + j;
      int hw = ni * 16 + (lane & 15);
      ob[(size_t)o * HW_ + hw] = acc[ni][j];
    }
}

extern "C" void kernel_launch(void* const* d_in, const int* in_sizes, int n_in,
                              void* d_out, int out_size, void* d_ws, size_t ws_size,
                              hipStream_t stream) {
  const float* inp  = (const float*)d_in[0];
  const float* filt = (const float*)d_in[1];
  const float* offs = (const float*)d_in[2];
  const float* msk  = (const float*)d_in[3];
  float* out = (float*)d_out;
  if (ws_size < ABF_OFF + ABF_BYTES) return;  // ~9.6 MB scratch
  unsigned short* nhwc = (unsigned short*)d_ws;
  unsigned short* abf2 = (unsigned short*)((char*)d_ws + ABF_OFF);

  k_nchw_to_nhwc<<<1024, 256, 0, stream>>>(inp, nhwc);
  k_prep_filter<<<256, 256, 0, stream>>>(filt, abf2);
  k_dcn_gemm<<<256, 1024, 0, stream>>>(nhwc, abf2, offs, msk, out);
}